// Round 5
// baseline (60.928 us; speedup 1.0000x reference)
//
#include <hip/hip_runtime.h>
#include <hip/hip_bf16.h>

#define B_ 8
#define W_ 128
#define K_ 2048
#define D_ 256
#define WX 144            // padded w-dim: 128 x-cols + E1-col(128) + 15 zero cols
#define NC 256            // K/8 j-chunks

typedef __attribute__((ext_vector_type(8))) short bf16x8;
typedef __attribute__((ext_vector_type(4))) float f32x4;

static __device__ __forceinline__ short f2bf(float f) {
    unsigned int u = __float_as_uint(f);
    unsigned int r = (u + 0x7FFFu + ((u >> 16) & 1u)) >> 16;
    return (short)r;
}
static __device__ __forceinline__ float bf2f(short s) {
    unsigned int u = ((unsigned int)(unsigned short)s) << 16;
    return __uint_as_float(u);
}

// ---------- k_prep: w2v (redundant per block) -> u2[b,k] + xbt (bf16, blocked, unscaled)
// xbt[b][c=j/8][w(0..143)][e=j%8]; w=128 col = 1.0 (becomes E1 after k_scale), 129+ = 0
__global__ __launch_bounds__(256) void k_prep(const float* __restrict__ x,
        const float* __restrict__ W_lin, const float* __restrict__ a,
        float* __restrict__ u2, short* __restrict__ xbt) {
    __shared__ float ws[W_];
    __shared__ float red2[2][W_];
    __shared__ float red[8][32];
    int tid = threadIdx.x;
    // w2v prologue: ws[w] = sum_d W_lin[128+w][d] * a[d]
    {
        int w = tid & 127, h = tid >> 7;
        const float4* rp = (const float4*)(W_lin + (size_t)(W_ + w) * D_) + h * 32;
        const float4* ap = (const float4*)a + h * 32;
        float acc = 0.f;
#pragma unroll 8
        for (int d = 0; d < 32; ++d) {
            float4 rv = rp[d], av = ap[d];
            acc += rv.x * av.x + rv.y * av.y + rv.z * av.z + rv.w * av.w;
        }
        red2[h][w] = acc;
    }
    __syncthreads();
    if (tid < W_) ws[tid] = red2[0][tid] + red2[1][tid];
    __syncthreads();

    int q = tid & 31;       // k within block
    int cw = tid >> 5;      // w chunk (16 w each)
    int bk0 = blockIdx.x * 32;
    int bk = bk0 + q;
    int b = bk >> 11;
    int k = bk & (K_ - 1);
    const float* xp = x + ((size_t)b * W_ + cw * 16) * K_ + k;
    short* xo = xbt + (((size_t)b * NC + (k >> 3)) * WX + cw * 16) * 8 + (k & 7);
    float acc = 0.f;
#pragma unroll
    for (int w = 0; w < 16; ++w) {
        float xv = xp[(size_t)w * K_];
        acc += xv * ws[cw * 16 + w];
        xo[w * 8] = f2bf(xv);
    }
    red[cw][q] = acc;
    // extra columns: w=128 -> 1.0, w=129..143 -> 0  (4 c-chunks per block)
    if (tid < 64) {
        int cl = tid >> 4;           // 0..3
        int wc = 128 + (tid & 15);
        short val = ((tid & 15) == 0) ? (short)0x3F80 : (short)0;
        bf16x8 vv;
#pragma unroll
        for (int e = 0; e < 8; ++e) vv[e] = val;
        size_t c = (size_t)((bk0 & (K_ - 1)) >> 3) + cl;
        *(bf16x8*)(xbt + (((size_t)b * NC + c) * WX + wc) * 8) = vv;
    }
    __syncthreads();
    if (tid < 32) {
        float s = 0.f;
#pragma unroll
        for (int cc = 0; cc < 8; ++cc) s += red[cc][tid];
        u2[bk0 + tid] = s;
    }
}

// ---------- k_e2: per-row rowmax + E2 = bf16(exp(bias - mb)) in blocked layout
// e2t[c=j/8][i][e=j%8]; one block per row i
__global__ __launch_bounds__(256) void k_e2(const float* __restrict__ bias,
                                            short* __restrict__ e2t) {
    __shared__ float red[256];
    int i = blockIdx.x, t = threadIdx.x;
    const float4* bp = (const float4*)(bias + (size_t)i * K_) + t * 2;
    float4 v0 = bp[0], v1 = bp[1];
    float m = fmaxf(fmaxf(fmaxf(v0.x, v0.y), fmaxf(v0.z, v0.w)),
                    fmaxf(fmaxf(v1.x, v1.y), fmaxf(v1.z, v1.w)));
    red[t] = m;
    __syncthreads();
    for (int s = 128; s > 0; s >>= 1) {
        if (t < s) red[t] = fmaxf(red[t], red[t + s]);
        __syncthreads();
    }
    float mb = red[0];
    bf16x8 o;
    o[0] = f2bf(__expf(v0.x - mb)); o[1] = f2bf(__expf(v0.y - mb));
    o[2] = f2bf(__expf(v0.z - mb)); o[3] = f2bf(__expf(v0.w - mb));
    o[4] = f2bf(__expf(v1.x - mb)); o[5] = f2bf(__expf(v1.y - mb));
    o[6] = f2bf(__expf(v1.z - mb)); o[7] = f2bf(__expf(v1.w - mb));
    *(bf16x8*)(e2t + ((size_t)t * K_ + i) * 8) = o;   // c = t
}

// ---------- k_scale: xbt *= E1[b,j]  (E1 = exp(u2 - umax), umax redundant per block)
// grid (16 cg, 8 b); block scales 16 c-chunks x 144 w
__global__ __launch_bounds__(256) void k_scale(const float* __restrict__ u2,
                                               short* __restrict__ xbt) {
    __shared__ float red[256];
    __shared__ float e1[128];
    int cg = blockIdx.x, b = blockIdx.y, t = threadIdx.x;
    const float4* up = (const float4*)(u2 + (size_t)b * K_) + t * 2;
    float4 v0 = up[0], v1 = up[1];
    float m = fmaxf(fmaxf(fmaxf(v0.x, v0.y), fmaxf(v0.z, v0.w)),
                    fmaxf(fmaxf(v1.x, v1.y), fmaxf(v1.z, v1.w)));
    red[t] = m;
    __syncthreads();
    for (int s = 128; s > 0; s >>= 1) {
        if (t < s) red[t] = fmaxf(red[t], red[t + s]);
        __syncthreads();
    }
    float umax = red[0];
    if (t < 128) e1[t] = __expf(u2[(size_t)b * K_ + cg * 128 + t] - umax);
    __syncthreads();
    // 16 c * 144 w = 2304 chunks, 9 per thread
#pragma unroll
    for (int s = 0; s < 9; ++s) {
        int id = t + s * 256;
        int cl = id / WX, w = id - cl * WX;
        size_t off = (((size_t)b * NC + cg * 16 + cl) * WX + w) * 8;
        bf16x8 v = *(bf16x8*)(xbt + off);
        bf16x8 o;
#pragma unroll
        for (int e = 0; e < 8; ++e) o[e] = f2bf(bf2f(v[e]) * e1[cl * 8 + e]);
        *(bf16x8*)(xbt + off) = o;
    }
}

// ---------- k_attn: pure GEMM  D[i, wcol] = sum_j E2[i,j] * X'[wcol, j]; col 128 = l
// grid (64, 8), 512 threads = 8 waves; block = 32 rows; wave = 32 rows x 256 j (j-split 8)
struct SetG {
    bf16x8 A0, A1;
    bf16x8 B0, B1, B2, B3, B4, B5, B6, B7, B8;
};

#define FETCHG(S, c_) do {                                         \
    const short* _e = eA + (size_t)(c_) * (K_ * 8);                \
    const short* _x = xB + (size_t)(c_) * (WX * 8);                \
    S.A0 = *(const bf16x8*)(_e);                                   \
    S.A1 = *(const bf16x8*)(_e + 128);                             \
    S.B0 = *(const bf16x8*)(_x);                                   \
    S.B1 = *(const bf16x8*)(_x + 128);                             \
    S.B2 = *(const bf16x8*)(_x + 256);                             \
    S.B3 = *(const bf16x8*)(_x + 384);                             \
    S.B4 = *(const bf16x8*)(_x + 512);                             \
    S.B5 = *(const bf16x8*)(_x + 640);                             \
    S.B6 = *(const bf16x8*)(_x + 768);                             \
    S.B7 = *(const bf16x8*)(_x + 896);                             \
    S.B8 = *(const bf16x8*)(_x + 1024);                            \
} while (0)

#define MF(a_, b_, c_) __builtin_amdgcn_mfma_f32_16x16x32_bf16(a_, b_, c_, 0, 0, 0)

#define CONSUMEG(S) do {                                           \
    acc0[0] = MF(S.A0, S.B0, acc0[0]); acc1[0] = MF(S.A1, S.B0, acc1[0]); \
    acc0[1] = MF(S.A0, S.B1, acc0[1]); acc1[1] = MF(S.A1, S.B1, acc1[1]); \
    acc0[2] = MF(S.A0, S.B2, acc0[2]); acc1[2] = MF(S.A1, S.B2, acc1[2]); \
    acc0[3] = MF(S.A0, S.B3, acc0[3]); acc1[3] = MF(S.A1, S.B3, acc1[3]); \
    acc0[4] = MF(S.A0, S.B4, acc0[4]); acc1[4] = MF(S.A1, S.B4, acc1[4]); \
    acc0[5] = MF(S.A0, S.B5, acc0[5]); acc1[5] = MF(S.A1, S.B5, acc1[5]); \
    acc0[6] = MF(S.A0, S.B6, acc0[6]); acc1[6] = MF(S.A1, S.B6, acc1[6]); \
    acc0[7] = MF(S.A0, S.B7, acc0[7]); acc1[7] = MF(S.A1, S.B7, acc1[7]); \
    acc0[8] = MF(S.A0, S.B8, acc0[8]); acc1[8] = MF(S.A1, S.B8, acc1[8]); \
} while (0)

__global__ __launch_bounds__(512) void k_attn(const short* __restrict__ e2t,
        const short* __restrict__ xbt, float* __restrict__ out) {
    __shared__ __align__(16) char ldsbuf[73728];   // 4 slots x 18 x 64 x f32x4
    int b    = blockIdx.y;
    int i0   = blockIdx.x * 32;
    int tid  = threadIdx.x;
    int wid  = tid >> 6;
    int lane = tid & 63;
    int il   = lane & 15;
    int kg   = lane >> 4;

    const short* eA = e2t + ((size_t)kg * K_ + i0 + il) * 8;           // A: rows i0+il(+16)
    const short* xB = xbt + (((size_t)b * NC + kg) * WX + il) * 8;     // B: w = n*16+il

    f32x4 acc0[9], acc1[9];
#pragma unroll
    for (int n = 0; n < 9; ++n) { acc0[n] = (f32x4){0,0,0,0}; acc1[n] = (f32x4){0,0,0,0}; }

    SetG X, Y;
    int c0 = wid * 32;                  // 32 c-chunks (256 j) per wave; 4 c per MFMA k-step
    FETCHG(X, c0);
    for (int s = 0; s < 8; s += 2) {
        FETCHG(Y, c0 + 4);
        CONSUMEG(X);
        if (s + 2 < 8) FETCHG(X, c0 + 8);
        CONSUMEG(Y);
        c0 += 8;
    }

    // 3-stage cross-wave tree reduction (8 -> 4 -> 2 -> 1)
    f32x4* R = (f32x4*)ldsbuf;
#define DUMPG(slot) do {                                            \
    _Pragma("unroll") for (int n = 0; n < 9; ++n) {                 \
        R[((slot) * 18 + n) * 64 + lane] = acc0[n];                 \
        R[((slot) * 18 + 9 + n) * 64 + lane] = acc1[n]; } } while (0)
#define GATHG(slot) do {                                            \
    _Pragma("unroll") for (int n = 0; n < 9; ++n) {                 \
        acc0[n] += R[((slot) * 18 + n) * 64 + lane];                \
        acc1[n] += R[((slot) * 18 + 9 + n) * 64 + lane]; } } while (0)

    if (wid >= 4) DUMPG(wid - 4);
    __syncthreads();
    if (wid < 4) GATHG(wid);
    __syncthreads();
    if (wid == 2 || wid == 3) DUMPG(wid - 2);
    __syncthreads();
    if (wid < 2) GATHG(wid);
    __syncthreads();
    if (wid == 1) DUMPG(0);
    __syncthreads();
    if (wid == 0) {
        GATHG(0);
        float* arr = (float*)ldsbuf;   // [col 144][36]  (36 = padded row dim)
#pragma unroll
        for (int n = 0; n < 9; ++n) {
            *(f32x4*)(arr + (n * 16 + il) * 36 + kg * 4)      = acc0[n];
            *(f32x4*)(arr + (n * 16 + il) * 36 + 16 + kg * 4) = acc1[n];
        }
    }
    __syncthreads();

    // epilogue: all 512 threads; col = tid>>2 (0..127), rows rs..rs+7
    {
        float* arr = (float*)ldsbuf;
        int col = tid >> 2;
        int rs  = (tid & 3) * 8;
        f32x4 n0 = *(f32x4*)(arr + col * 36 + rs);
        f32x4 n1 = *(f32x4*)(arr + col * 36 + rs + 4);
        f32x4 l0 = *(f32x4*)(arr + 128 * 36 + rs);
        f32x4 l1 = *(f32x4*)(arr + 128 * 36 + rs + 4);
        float4 o0, o1;
        o0.x = 1.f / (1.f + __expf(-n0[0] / l0[0]));
        o0.y = 1.f / (1.f + __expf(-n0[1] / l0[1]));
        o0.z = 1.f / (1.f + __expf(-n0[2] / l0[2]));
        o0.w = 1.f / (1.f + __expf(-n0[3] / l0[3]));
        o1.x = 1.f / (1.f + __expf(-n1[0] / l1[0]));
        o1.y = 1.f / (1.f + __expf(-n1[1] / l1[1]));
        o1.z = 1.f / (1.f + __expf(-n1[2] / l1[2]));
        o1.w = 1.f / (1.f + __expf(-n1[3] / l1[3]));
        float* op = out + ((size_t)b * W_ + col) * K_ + i0 + rs;
        *(float4*)op = o0;
        *(float4*)(op + 4) = o1;
    }
}

extern "C" void kernel_launch(void* const* d_in, const int* in_sizes, int n_in,
                              void* d_out, int out_size, void* d_ws, size_t ws_size,
                              hipStream_t stream) {
    const float* x     = (const float*)d_in[0];
    const float* W_lin = (const float*)d_in[1];
    // d_in[2] = b_lin: constant along softmax axis -> cancels, unused
    const float* a     = (const float*)d_in[3];
    const float* bias  = (const float*)d_in[4];
    float* out = (float*)d_out;

    float* u2  = (float*)d_ws;                    // 16384 f32
    short* xbt = (short*)(u2 + B_ * K_);          // 8*256*144*8 = 2,359,296 bf16 (4.72 MB)
    short* e2t = xbt + (size_t)B_ * NC * WX * 8;  // 256*2048*8 = 4,194,304 bf16 (8 MB)

    k_prep <<<(B_ * K_) / 32, 256, 0, stream>>>(x, W_lin, a, u2, xbt);
    k_e2   <<<K_, 256, 0, stream>>>(bias, e2t);
    k_scale<<<dim3(16, B_), 256, 0, stream>>>(u2, xbt);
    k_attn <<<dim3(K_ / 32, B_), 512, 0, stream>>>(e2t, xbt, out);
}

// Round 6
// 53.134 us; speedup vs baseline: 1.1467x; 1.1467x over previous
//
#include <hip/hip_runtime.h>
#include <hip/hip_bf16.h>

#define B_ 8
#define W_ 128
#define K_ 2048
#define D_ 256
#define WX 144            // padded w-dim: 128 x-cols + E1-col(128) + 15 zero cols
#define NC 256            // K/8 j-chunks

typedef __attribute__((ext_vector_type(8))) short bf16x8;
typedef __attribute__((ext_vector_type(4))) float f32x4;

static __device__ __forceinline__ short f2bf(float f) {
    unsigned int u = __float_as_uint(f);
    unsigned int r = (u + 0x7FFFu + ((u >> 16) & 1u)) >> 16;
    return (short)r;
}

// ---------- k_w2v: w2v[w] = sum_d W_lin[W+w][d] * a[d]  (128 blocks x 1 wave)
__global__ void k_w2v(const float* __restrict__ W_lin, const float* __restrict__ a,
                      float* __restrict__ w2v) {
    int w = blockIdx.x, l = threadIdx.x;
    float4 rv = ((const float4*)(W_lin + (size_t)(W_ + w) * D_))[l];
    float4 av = ((const float4*)a)[l];
    float acc = rv.x * av.x + rv.y * av.y + rv.z * av.z + rv.w * av.w;
    for (int m = 1; m < 64; m <<= 1) acc += __shfl_xor(acc, m);
    if (l == 0) w2v[w] = acc;
}

// ---------- k_prep: one pass: u2 reduce -> E1=exp(u2) -> xbt = bf16(x*E1), blocked
// xbt[b][c=j/8][w 0..143][e=j%8]; col 128 = E1, cols 129..143 = 0.
// grid 512 blocks (32 k-cols each), 256 thr = 32 k x 8 w-chunks.
__global__ __launch_bounds__(256) void k_prep(const float* __restrict__ x,
        const float* __restrict__ w2v, short* __restrict__ xbt) {
    __shared__ float ws[W_];
    __shared__ float red[8][33];
    __shared__ float e1s[32];
    int tid = threadIdx.x;
    if (tid < W_) ws[tid] = w2v[tid];
    __syncthreads();
    int q = tid & 31, cw = tid >> 5;
    int bk0 = blockIdx.x * 32;
    int b = bk0 >> 11;
    int k = (bk0 & (K_ - 1)) + q;
    const float* xp = x + ((size_t)b * W_ + cw * 16) * K_ + k;
    float xv[16];
    float acc = 0.f;
#pragma unroll
    for (int w = 0; w < 16; ++w) {
        xv[w] = xp[(size_t)w * K_];
        acc += xv[w] * ws[cw * 16 + w];
    }
    red[cw][q] = acc;
    __syncthreads();
    if (tid < 32) {
        float s = 0.f;
#pragma unroll
        for (int cc = 0; cc < 8; ++cc) s += red[cc][tid];
        e1s[tid] = __expf(s);     // no max-shift: |u2| < ~6, exp safe; softmax shift-invariant
    }
    __syncthreads();
    float e1q = e1s[q];
    short* xo = xbt + (((size_t)b * NC + (k >> 3)) * WX + cw * 16) * 8 + (k & 7);
#pragma unroll
    for (int w = 0; w < 16; ++w) xo[w * 8] = f2bf(xv[w] * e1q);
    // E1 column (w=128)
    if (tid < 32) {
        int kk = (bk0 & (K_ - 1)) + tid;
        xbt[(((size_t)b * NC + (kk >> 3)) * WX + 128) * 8 + (kk & 7)] = f2bf(e1s[tid]);
    }
    // zero cols 129..143 for this block's 4 c-chunks
    if (tid >= 64 && tid < 124) {
        int id = tid - 64;
        int cl = id / 15, wz = 129 + id % 15;
        int c = ((bk0 & (K_ - 1)) >> 3) + cl;
        bf16x8 z = {0, 0, 0, 0, 0, 0, 0, 0};
        *(bf16x8*)(xbt + (((size_t)b * NC + c) * WX + wz) * 8) = z;
    }
}

// ---------- k_e2: E2 = bf16(exp(bias - rowmax)) in blocked layout e2t[c][i][e]
// 128 blocks x 16 rows. Phase1: coalesced rowmax. Phase2: writes with i innermost.
__global__ __launch_bounds__(256) void k_e2(const float* __restrict__ bias,
                                            short* __restrict__ e2t) {
    __shared__ float mbs[16];
    int tid = threadIdx.x;
    int i0 = blockIdx.x * 16;
    {
        int r = tid >> 4, t16 = tid & 15;
        const float4* bp = (const float4*)(bias + (size_t)(i0 + r) * K_);
        float m = -1e30f;
#pragma unroll 8
        for (int s = 0; s < 32; ++s) {
            float4 v = bp[t16 + s * 16];
            m = fmaxf(m, fmaxf(fmaxf(v.x, v.y), fmaxf(v.z, v.w)));
        }
#pragma unroll
        for (int mm = 1; mm < 16; mm <<= 1) m = fmaxf(m, __shfl_xor(m, mm));
        if (t16 == 0) mbs[r] = m;
    }
    __syncthreads();
    int il = tid & 15, cg = tid >> 4;
    float mb = mbs[il];
    int i = i0 + il;
    const float4* brow = (const float4*)(bias + (size_t)i * K_);
#pragma unroll 4
    for (int it = 0; it < 16; ++it) {
        int c = cg * 16 + it;
        float4 v0 = brow[c * 2];
        float4 v1 = brow[c * 2 + 1];
        bf16x8 o;
        o[0] = f2bf(__expf(v0.x - mb)); o[1] = f2bf(__expf(v0.y - mb));
        o[2] = f2bf(__expf(v0.z - mb)); o[3] = f2bf(__expf(v0.w - mb));
        o[4] = f2bf(__expf(v1.x - mb)); o[5] = f2bf(__expf(v1.y - mb));
        o[6] = f2bf(__expf(v1.z - mb)); o[7] = f2bf(__expf(v1.w - mb));
        *(bf16x8*)(e2t + ((size_t)c * K_ + i) * 8) = o;   // 16 il-lanes -> 256B runs
    }
}

// ---------- k_attn: pure GEMM D[i,wcol] = sum_j E2[i,j]*X'[wcol,j]; col 128 = l
// 1D grid 512: b = blk&7 (XCD-local), i0 = (blk>>3)*32. 512 thr = 8 waves,
// wave = 2 m-tiles (A0,A1) x 9 n x 256-j slice (8-way j-split). Single-buffered;
// launch_bounds(512,4) caps VGPR<=128 -> 2 blocks/CU = 4 waves/SIMD.
struct SetG {
    bf16x8 A0, A1;
    bf16x8 B0, B1, B2, B3, B4, B5, B6, B7, B8;
};

#define FETCHG(S, c_) do {                                         \
    const short* _e = eA + (size_t)(c_) * (K_ * 8);                \
    const short* _x = xB + (size_t)(c_) * (WX * 8);                \
    S.A0 = *(const bf16x8*)(_e);                                   \
    S.A1 = *(const bf16x8*)(_e + 128);                             \
    S.B0 = *(const bf16x8*)(_x);                                   \
    S.B1 = *(const bf16x8*)(_x + 128);                             \
    S.B2 = *(const bf16x8*)(_x + 256);                             \
    S.B3 = *(const bf16x8*)(_x + 384);                             \
    S.B4 = *(const bf16x8*)(_x + 512);                             \
    S.B5 = *(const bf16x8*)(_x + 640);                             \
    S.B6 = *(const bf16x8*)(_x + 768);                             \
    S.B7 = *(const bf16x8*)(_x + 896);                             \
    S.B8 = *(const bf16x8*)(_x + 1024);                            \
} while (0)

#define MF(a_, b_, c_) __builtin_amdgcn_mfma_f32_16x16x32_bf16(a_, b_, c_, 0, 0, 0)

#define CONSUMEG(S) do {                                           \
    acc0[0] = MF(S.A0, S.B0, acc0[0]); acc1[0] = MF(S.A1, S.B0, acc1[0]); \
    acc0[1] = MF(S.A0, S.B1, acc0[1]); acc1[1] = MF(S.A1, S.B1, acc1[1]); \
    acc0[2] = MF(S.A0, S.B2, acc0[2]); acc1[2] = MF(S.A1, S.B2, acc1[2]); \
    acc0[3] = MF(S.A0, S.B3, acc0[3]); acc1[3] = MF(S.A1, S.B3, acc1[3]); \
    acc0[4] = MF(S.A0, S.B4, acc0[4]); acc1[4] = MF(S.A1, S.B4, acc1[4]); \
    acc0[5] = MF(S.A0, S.B5, acc0[5]); acc1[5] = MF(S.A1, S.B5, acc1[5]); \
    acc0[6] = MF(S.A0, S.B6, acc0[6]); acc1[6] = MF(S.A1, S.B6, acc1[6]); \
    acc0[7] = MF(S.A0, S.B7, acc0[7]); acc1[7] = MF(S.A1, S.B7, acc1[7]); \
    acc0[8] = MF(S.A0, S.B8, acc0[8]); acc1[8] = MF(S.A1, S.B8, acc1[8]); \
} while (0)

__global__ __launch_bounds__(512, 4) void k_attn(const short* __restrict__ e2t,
        const short* __restrict__ xbt, float* __restrict__ out) {
    __shared__ __align__(16) char ldsbuf[73728];   // 4 slots x 18 x 64 x f32x4
    int blk  = blockIdx.x;
    int b    = blk & 7;                 // XCD-aligned: round-robin dispatch -> same b per XCD
    int i0   = (blk >> 3) * 32;
    int tid  = threadIdx.x;
    int wid  = tid >> 6;
    int lane = tid & 63;
    int il   = lane & 15;
    int kg   = lane >> 4;

    const short* eA = e2t + ((size_t)kg * K_ + i0 + il) * 8;
    const short* xB = xbt + (((size_t)b * NC + kg) * WX + il) * 8;

    f32x4 acc0[9], acc1[9];
#pragma unroll
    for (int n = 0; n < 9; ++n) { acc0[n] = (f32x4){0,0,0,0}; acc1[n] = (f32x4){0,0,0,0}; }

    SetG X;
    int c0 = wid * 32;                  // 32 c-chunks = 256 j per wave, 8 k-steps
    for (int s = 0; s < 8; ++s) {
        FETCHG(X, c0 + s * 4);
        CONSUMEG(X);
    }

    // 3-stage cross-wave tree reduction (8 -> 4 -> 2 -> 1)
    f32x4* R = (f32x4*)ldsbuf;
#define DUMPG(slot) do {                                            \
    _Pragma("unroll") for (int n = 0; n < 9; ++n) {                 \
        R[((slot) * 18 + n) * 64 + lane] = acc0[n];                 \
        R[((slot) * 18 + 9 + n) * 64 + lane] = acc1[n]; } } while (0)
#define GATHG(slot) do {                                            \
    _Pragma("unroll") for (int n = 0; n < 9; ++n) {                 \
        acc0[n] += R[((slot) * 18 + n) * 64 + lane];                \
        acc1[n] += R[((slot) * 18 + 9 + n) * 64 + lane]; } } while (0)

    if (wid >= 4) DUMPG(wid - 4);
    __syncthreads();
    if (wid < 4) GATHG(wid);
    __syncthreads();
    if (wid == 2 || wid == 3) DUMPG(wid - 2);
    __syncthreads();
    if (wid < 2) GATHG(wid);
    __syncthreads();
    if (wid == 1) DUMPG(0);
    __syncthreads();
    if (wid == 0) {
        GATHG(0);
        float* arr = (float*)ldsbuf;   // [col 144][36 padded rows] = 20.7 KB
#pragma unroll
        for (int n = 0; n < 9; ++n) {
            *(f32x4*)(arr + (n * 16 + il) * 36 + kg * 4)      = acc0[n];
            *(f32x4*)(arr + (n * 16 + il) * 36 + 16 + kg * 4) = acc1[n];
        }
    }
    __syncthreads();

    // epilogue: col = tid>>2 (0..127), rows rs..rs+7; l in col 128
    {
        float* arr = (float*)ldsbuf;
        int col = tid >> 2;
        int rs  = (tid & 3) * 8;
        f32x4 n0 = *(f32x4*)(arr + col * 36 + rs);
        f32x4 n1 = *(f32x4*)(arr + col * 36 + rs + 4);
        f32x4 l0 = *(f32x4*)(arr + 128 * 36 + rs);
        f32x4 l1 = *(f32x4*)(arr + 128 * 36 + rs + 4);
        float4 o0, o1;
        o0.x = 1.f / (1.f + __expf(-n0[0] / l0[0]));
        o0.y = 1.f / (1.f + __expf(-n0[1] / l0[1]));
        o0.z = 1.f / (1.f + __expf(-n0[2] / l0[2]));
        o0.w = 1.f / (1.f + __expf(-n0[3] / l0[3]));
        o1.x = 1.f / (1.f + __expf(-n1[0] / l1[0]));
        o1.y = 1.f / (1.f + __expf(-n1[1] / l1[1]));
        o1.z = 1.f / (1.f + __expf(-n1[2] / l1[2]));
        o1.w = 1.f / (1.f + __expf(-n1[3] / l1[3]));
        float* op = out + ((size_t)b * W_ + col) * K_ + i0 + rs;
        *(float4*)op = o0;
        *(float4*)(op + 4) = o1;
    }
}

extern "C" void kernel_launch(void* const* d_in, const int* in_sizes, int n_in,
                              void* d_out, int out_size, void* d_ws, size_t ws_size,
                              hipStream_t stream) {
    const float* x     = (const float*)d_in[0];
    const float* W_lin = (const float*)d_in[1];
    // d_in[2] = b_lin: constant along softmax axis -> cancels, unused
    const float* a     = (const float*)d_in[3];
    const float* bias  = (const float*)d_in[4];
    float* out = (float*)d_out;

    float* w2v = (float*)d_ws;                    // 128 f32
    short* xbt = (short*)(w2v + 128);             // 8*256*144*8 bf16 = 4.72 MB
    short* e2t = xbt + (size_t)B_ * NC * WX * 8;  // 256*2048*8 bf16 = 8 MB

    k_w2v <<<128, 64, 0, stream>>>(W_lin, a, w2v);
    k_prep<<<(B_ * K_) / 32, 256, 0, stream>>>(x, w2v, xbt);
    k_e2  <<<K_ / 16, 256, 0, stream>>>(bias, e2t);
    k_attn<<<512, 512, 0, stream>>>(e2t, xbt, out);
}